// Round 16
// baseline (351.676 us; speedup 1.0000x reference)
//
#include <hip/hip_runtime.h>

#define NPTS 4096
#define NQ   8192      // B*N
#define DD   64
#define KNN  16
#define KC   8
#define NSEG3 32       // exact knn3/rigid streams (seg length 128)
#define NPSF 64        // psegs for knnf packed path (4 segs x 16 p-streams)
#define NPSV 32        // psegs for knnv packed path
#define KB96 96        // bf16 feature row: 67 real + 29 zeros
#define FSTR 104       // padded LDS row stride (shorts) = 13 float4 (odd -> no conflicts)
#define VOFF 1048576   // B*128*N, float offset of v_world in d_out

#define ALWAYS_INLINE __attribute__((always_inline)) inline

typedef __attribute__((ext_vector_type(8))) short bf16x8;
typedef __attribute__((ext_vector_type(4))) float f32x4;

__device__ ALWAYS_INLINE float leakyf(float x) { return x > 0.f ? x : 0.1f * x; }

__device__ ALWAYS_INLINE unsigned short bf16rne(float f) {
  unsigned u = __float_as_uint(f);
  u = (u + 0x7FFFu + ((u >> 16) & 1u)) >> 16;
  return (unsigned short)u;
}

// Pack distance + 12-bit tag into one f32 sort key (d>=0 so float cmp == uint cmp).
__device__ ALWAYS_INLINE float packdt(float d, unsigned tag12) {
  return __uint_as_float((__float_as_uint(d) & 0xFFFFF000u) | tag12);
}

// ---- top-k state as NAMED SCALARS (never arrays — hipcc scratch-allocates
// per-thread arrays: rounds 1-4 measured 5-10x slowdown from this) ----
#define TK8_FOREACH(M)  M(0) M(1) M(2) M(3) M(4) M(5) M(6) M(7)
#define TK16_FOREACH(M) M(0) M(1) M(2) M(3) M(4) M(5) M(6) M(7) \
                        M(8) M(9) M(10) M(11) M(12) M(13) M(14) M(15)

#define TK_DECL1(i) float tkd##i = 3.4e38f; int tki##i = 0;
#define TK_STEP1(i) { bool c = vd < tkd##i; float t_ = tkd##i; int u_ = tki##i; \
                      tkd##i = c ? vd : tkd##i; tki##i = c ? vi : tki##i; \
                      vd = c ? t_ : vd; vi = c ? u_ : vi; }
#define TK8_DECL  TK8_FOREACH(TK_DECL1)
#define TK8_INS(dexp, mexp)  { float vd = (dexp); int vi = (mexp); \
                               if (vd < tkd7)  { TK8_FOREACH(TK_STEP1) } }
#define TK8_RESET1(i) tkd##i = 3.4e38f; tki##i = 0;

#define PK_DECL1(i) float pk##i = __uint_as_float(0x7F7FFFFFu);
#define PK_RESET1(i) pk##i = __uint_as_float(0x7F7FFFFFu);
#define PK_STEP1(i) { float lo_ = fminf(pk##i, pv); pv = fmaxf(pk##i, pv); pk##i = lo_; }
#define PK16_DECL    TK16_FOREACH(PK_DECL1)
#define PK16_INS(ve) { float pv = (ve); TK16_FOREACH(PK_STEP1) }
#define PK_STORE1(i) pdq[i] = pk##i;
#define PK16_STORE   TK16_FOREACH(PK_STORE1)

// ------- prep: 64 points x 4 channel-parts per block (256 blocks, 2 clouds) -------
__global__ __launch_bounds__(256) void k_prep(
    const float* __restrict__ xyz1, const float* __restrict__ xyz2,
    const float* __restrict__ pts1, const float* __restrict__ pts2,
    const float* __restrict__ w_xyz_p, const float* __restrict__ w_points_p,
    unsigned short* __restrict__ f1b, unsigned short* __restrict__ f2b,
    float* __restrict__ n1, float* __restrict__ n2a,
    float* __restrict__ p1t, float* __restrict__ p2t,
    float* __restrict__ x1t, float* __restrict__ x2t)
{
  __shared__ float s_acc[64][5];
  int tid = threadIdx.x;
  int nl = tid & 63, part = tid >> 6;
  int cloud = blockIdx.x >> 7;
  int gid = ((blockIdx.x & 127) << 6) + nl;
  int b = gid >> 12, n = gid & (NPTS - 1);
  float wx = w_xyz_p[0], wp = w_points_p[0];
  const float* xyz = cloud ? xyz2 : xyz1;
  const float* pts = cloud ? pts2 : pts1;
  unsigned short* fb = cloud ? f2b : f1b;
  float* nrm = cloud ? n2a : n1;
  float* pt  = cloud ? p2t : p1t;
  float* xt  = cloud ? x2t : x1t;
  const float* pb = pts + (size_t)b * DD * NPTS;
  float* pr = pt + (size_t)gid * DD;
  unsigned short* fr = fb + (size_t)gid * KB96;
  int c0 = part * 16;
  float acc = 0.f;
#pragma unroll 4
  for (int j = 0; j < 16; ++j) {
    float v = pb[(size_t)(c0 + j) * NPTS + n];
    pr[c0 + j] = v;
    float fv = wp * v;
    fr[3 + c0 + j] = bf16rne(fv);
    acc = fmaf(fv, fv, acc);
  }
  s_acc[nl][part] = acc;
  if (part == 1) { for (int c = 67; c < 82; ++c) fr[c] = 0; }
  else if (part == 2) { for (int c = 82; c < KB96; ++c) fr[c] = 0; }
  __syncthreads();
  if (part == 0) {
    const float* xb = xyz + (size_t)b * 3 * NPTS;
    float x = xb[n], y = xb[NPTS + n], z = xb[2 * NPTS + n];
    float nrm2 = fmaf(z, z, fmaf(y, y, x * x));
    float4 xv; xv.x = x; xv.y = y; xv.z = z; xv.w = nrm2;
    *(float4*)&xt[(size_t)gid * 4] = xv;
    float fx = wx * x, fy = wx * y, fz = wx * z;
    fr[0] = bf16rne(fx); fr[1] = bf16rne(fy); fr[2] = bf16rne(fz);
    float a = fmaf(fz, fz, fmaf(fy, fy, fx * fx));
    a += s_acc[nl][0] + s_acc[nl][1] + s_acc[nl][2] + s_acc[nl][3];
    nrm[gid] = a;
  }
}

// ------- knn over xyz1, 32 segs x 128 candidates, K=8 EXACT (feeds rigid) -------
__global__ __launch_bounds__(256) void k_knn3(
    const float* __restrict__ x4, float* __restrict__ pd, int* __restrict__ pi)
{
  __shared__ __align__(16) float4 sc[128];
  int seg = blockIdx.y;                       // 0..31
  int Q = blockIdx.x * 256 + threadIdx.x;
  int b = Q >> 12;
  float4 q = *(const float4*)&x4[(size_t)Q * 4];
  TK8_DECL
  int gbase = (b << 12) + seg * 128;
  if (threadIdx.x < 128)
    sc[threadIdx.x] = *(const float4*)&x4[(size_t)(gbase + threadIdx.x) * 4];
  __syncthreads();
  int m0 = seg * 128;
#pragma unroll
  for (int j = 0; j < 128; ++j) {
    float4 c = sc[j];
    float dot = fmaf(q.z, c.z, fmaf(q.y, c.y, q.x * c.x));
    float d = fmaxf(q.w + c.w - 2.f * dot, 0.f);
    TK8_INS(d, m0 + j)
  }
  float* pdq = pd + ((size_t)Q * NSEG3 + seg) * 8;
  int* piq = pi + ((size_t)Q * NSEG3 + seg) * 8;
#define ST8(i) pdq[i] = tkd##i; piq[i] = tki##i;
  TK8_FOREACH(ST8)
#undef ST8
}

// ------- knn over v_world, 32 segs x 128 candidates, packed keys -------
__global__ __launch_bounds__(256) void k_knnv(
    const float* __restrict__ x4, float* __restrict__ pd)
{
  __shared__ __align__(16) float4 sc[128];
  int seg = blockIdx.y;                      // 0..31
  int Q = blockIdx.x * 256 + threadIdx.x;
  int b = Q >> 12;
  float4 q = *(const float4*)&x4[(size_t)Q * 4];
  PK16_DECL
  int gbase = (b << 12) + seg * 128;
  if (threadIdx.x < 128)
    sc[threadIdx.x] = *(const float4*)&x4[(size_t)(gbase + threadIdx.x) * 4];
  __syncthreads();
#pragma unroll
  for (int j = 0; j < 128; ++j) {
    float4 c = sc[j];
    float dot = fmaf(q.z, c.z, fmaf(q.y, c.y, q.x * c.x));
    float d = fmaxf(q.w + c.w - 2.f * dot, 0.f);
    PK16_INS(packdt(d, ((unsigned)j << 5) | (unsigned)seg))
  }
  float* pdq = pd + ((size_t)Q * NPSV + seg) * 16;
  PK16_STORE
}

// ------- merge 32x8 exact (4 threads/query) + rigid velocity regression -------
__global__ __launch_bounds__(256) void k_rigid(
    const float* __restrict__ pd, const int* __restrict__ pi,
    const float* __restrict__ x4, const float* __restrict__ vel1,
    float* __restrict__ vout, float* __restrict__ v4out)
{
  __shared__ __align__(16) float s_d[64][33];
  __shared__ __align__(16) int   s_i[64][33];
  int tid = threadIdx.x;
  int ql = tid >> 2, part = tid & 3;
  int Q = blockIdx.x * 64 + ql;
  int b = Q >> 12;
  TK8_DECL
  {
    int s0 = part * 8;
    const float* pbase = pd + ((size_t)Q * NSEG3 + s0) * 8;
    const int* ibase = pi + ((size_t)Q * NSEG3 + s0) * 8;
#pragma unroll
    for (int s = 0; s < 8; ++s) {
#pragma unroll
      for (int j = 0; j < 8; ++j) TK8_INS(pbase[s * 8 + j], ibase[s * 8 + j])
    }
  }
#define STP(i) s_d[ql][part * 8 + i] = tkd##i; s_i[ql][part * 8 + i] = tki##i;
  TK8_FOREACH(STP)
#undef STP
  __syncthreads();
  if (part != 0) return;
  TK8_FOREACH(TK8_RESET1)
#pragma unroll
  for (int j = 0; j < 32; ++j) TK8_INS(s_d[ql][j], s_i[ql][j])
  int base = b << 12;
  double a00 = 0, a01 = 0, a02 = 0, a11 = 0, a12 = 0, a22 = 0;
  double r0 = 0, r1 = 0, r2 = 0;
#define RIG_ACC(i) { \
    float4 c = *(const float4*)&x4[(size_t)(base + tki##i) * 4]; \
    float nr = sqrtf(c.w); \
    float ux = c.x / nr, uy = c.y / nr, uz = c.z / nr; \
    float cv = vel1[base + tki##i]; \
    double dx = ux, dy = uy, dz = uz, dvv = cv; \
    a00 += dx * dx; a01 += dx * dy; a02 += dx * dz; \
    a11 += dy * dy; a12 += dy * dz; a22 += dz * dz; \
    r0 += dx * dvv; r1 += dy * dvv; r2 += dz * dvv; }
  TK8_FOREACH(RIG_ACC)
#undef RIG_ACC
  a00 += 1e-6; a11 += 1e-6; a22 += 1e-6;
  double c00 = a11 * a22 - a12 * a12;
  double c01 = a02 * a12 - a01 * a22;
  double c02 = a01 * a12 - a02 * a11;
  double c11 = a00 * a22 - a02 * a02;
  double c12 = a02 * a01 - a00 * a12;
  double c22 = a00 * a11 - a01 * a01;
  double det = a00 * c00 + a01 * c01 + a02 * c02;
  double inv = 1.0 / det;
  float vx = (float)((c00 * r0 + c01 * r1 + c02 * r2) * inv);
  float vy = (float)((c01 * r0 + c11 * r1 + c12 * r2) * inv);
  float vz = (float)((c02 * r0 + c12 * r1 + c22 * r2) * inv);
  vout[(size_t)Q * 3 + 0] = vx;
  vout[(size_t)Q * 3 + 1] = vy;
  vout[(size_t)Q * 3 + 2] = vz;
  float4 v; v.x = vx; v.y = vy; v.z = vz;
  v.w = fmaf(vz, vz, fmaf(vy, vy, vx * vx));
  *(float4*)&v4out[(size_t)Q * 4] = v;
}

// ------- knnf via bf16 MFMA: 16 queries x 1024 candidates per block -------
// grid (512, 4) = 2048 blocks = 8/CU (was 4 -> TLP doubles). Single LDS buffer
// (double-buffer measured null in R12/R13) keeps LDS at ~22 KB (7 blocks/CU cap).
// 64 psegs: tag12 = local6<<6 | pseg6; local = ch*4+(crow&3), pseg = seg*16+(crow>>2).
__global__ __launch_bounds__(256) void k_knnf_mfma(
    const unsigned short* __restrict__ f1b, const unsigned short* __restrict__ f2b,
    const float* __restrict__ n1, const float* __restrict__ n2a,
    float* __restrict__ pd)
{
  __shared__ __align__(16) unsigned short sf1[16 * FSTR];
  __shared__ __align__(16) unsigned short sf2[64 * FSTR];
  __shared__ __align__(16) float sn1[16];
  __shared__ __align__(16) float sn2[64];
  __shared__ __align__(16) float sD[64][17];
  int tid = threadIdx.x;
  int w = tid >> 6, lane = tid & 63;
  int i15 = lane & 15, g = lane >> 4, kr0 = g * 8;
  int blockq = blockIdx.x * 16;
  int b = blockq >> 12;
  int seg = blockIdx.y;                       // 0..3 (1024 candidates each)
  int gbase = (b << 12) + seg * 1024;
  {
    const float4* src = (const float4*)(f1b + (size_t)blockq * KB96);
    if (tid < 192) ((float4*)sf1)[tid + tid / 12] = src[tid];   // 12 f4/row -> stride 13
    if (tid < 16) sn1[tid] = n1[blockq + tid];
  }
  __syncthreads();
  bf16x8 af0 = *(const bf16x8*)&sf1[i15 * FSTR + kr0];
  bf16x8 af1 = *(const bf16x8*)&sf1[i15 * FSTR + 32 + kr0];
  bf16x8 af2 = *(const bf16x8*)&sf1[i15 * FSTR + 64 + kr0];
  float nq0 = sn1[g * 4 + 0], nq1 = sn1[g * 4 + 1];
  float nq2 = sn1[g * 4 + 2], nq3 = sn1[g * 4 + 3];
  PK16_DECL
  int q_tk = tid & 15, p_tk = tid >> 4;       // 16 queries x 16 p-streams
  for (int ch = 0; ch < 16; ++ch) {
    __syncthreads();   // prev chunk's sf2/sD reads done
    {
      const float4* src = (const float4*)(f2b + (size_t)(gbase + ch * 64) * KB96);
      int i0 = tid, i1 = tid + 256, i2 = tid + 512;
      ((float4*)sf2)[i0 + i0 / 12] = src[i0];
      ((float4*)sf2)[i1 + i1 / 12] = src[i1];
      ((float4*)sf2)[i2 + i2 / 12] = src[i2];
      if (tid < 64) sn2[tid] = n2a[gbase + ch * 64 + tid];
    }
    __syncthreads();   // sf2/sn2 ready
    {
      int crow = w * 16 + i15;
      const unsigned short* c_ = &sf2[crow * FSTR + kr0];
      f32x4 acc = {0.f, 0.f, 0.f, 0.f};
      acc = __builtin_amdgcn_mfma_f32_16x16x32_bf16(af0, *(const bf16x8*)&c_[0],  acc, 0, 0, 0);
      acc = __builtin_amdgcn_mfma_f32_16x16x32_bf16(af1, *(const bf16x8*)&c_[32], acc, 0, 0, 0);
      acc = __builtin_amdgcn_mfma_f32_16x16x32_bf16(af2, *(const bf16x8*)&c_[64], acc, 0, 0, 0);
      float nn2 = sn2[crow];
      unsigned tag = (((unsigned)(ch * 4 + (crow & 3))) << 6) |
                     (unsigned)(seg * 16 + (crow >> 2));
      sD[crow][g * 4 + 0] = packdt(fmaxf(nq0 + nn2 - 2.f * acc[0], 0.f), tag);
      sD[crow][g * 4 + 1] = packdt(fmaxf(nq1 + nn2 - 2.f * acc[1], 0.f), tag);
      sD[crow][g * 4 + 2] = packdt(fmaxf(nq2 + nn2 - 2.f * acc[2], 0.f), tag);
      sD[crow][g * 4 + 3] = packdt(fmaxf(nq3 + nn2 - 2.f * acc[3], 0.f), tag);
    }
    __syncthreads();   // sD ready
#pragma unroll
    for (int j = 0; j < 4; ++j)
      PK16_INS(sD[p_tk * 4 + j][q_tk])
  }
  int pseg = seg * 16 + p_tk;
  float* pdq = pd + ((size_t)(blockq + q_tk) * NPSF + pseg) * 16;
  PK16_STORE
}

// ------- packed merges: sorted psegs -> top-16, decode global idx -------
// MODE 0 (knnf, 64 psegs): m = (ps>>4)*1024 + (lo>>2)*64 + (ps&15)*4 + (lo&3)
// MODE 1 (knnv, 32 psegs): m = ps*128 + lo
template<int MODE>
__global__ __launch_bounds__(256) void k_mergepk(
    const float* __restrict__ pd, int* __restrict__ oidx)
{
  constexpr int NPS = (MODE == 0) ? NPSF : NPSV;
  constexpr int PARTS = (MODE == 0) ? 8 : 4;
  constexpr int QPB = 256 / PARTS;
  __shared__ __align__(16) float s_k[QPB][PARTS * 16 + 1];
  int tid = threadIdx.x;
  int ql = tid / PARTS, part = tid % PARTS;
  int Q = blockIdx.x * QPB + ql;
  PK16_DECL
  {
    const float* pbase = pd + ((size_t)Q * NPS + part * 8) * 16;
#pragma unroll
    for (int s = 0; s < 8; ++s) {
      for (int j = 0; j < 16; ++j) {     // sorted ascending -> per-thread break exact
        float v = pbase[s * 16 + j];
        if (!(v < pk15)) break;
        PK16_INS(v)
      }
    }
  }
#define STK(i) s_k[ql][part * 16 + i] = pk##i;
  TK16_FOREACH(STK)
#undef STK
  __syncthreads();
  if (part != 0) return;
  TK16_FOREACH(PK_RESET1)
#pragma unroll
  for (int p = 0; p < PARTS; ++p) {
    for (int j = 0; j < 16; ++j) {
      float v = s_k[ql][p * 16 + j];
      if (!(v < pk15)) break;
      PK16_INS(v)
    }
  }
#define DEC(i) { unsigned u = __float_as_uint(pk##i); int m_; \
    if (MODE == 0) { unsigned ps = u & 63u, lo = (u >> 6) & 63u; \
      m_ = (int)(((ps >> 4) << 10) + ((lo >> 2) << 6) + ((ps & 15u) << 2) + (lo & 3u)); } \
    else { unsigned ps = u & 31u, lo = (u >> 5) & 127u; m_ = (int)((ps << 7) + lo); } \
    oidx[(size_t)Q * KNN + i] = m_; }
  TK16_FOREACH(DEC)
#undef DEC
}

// ---------------- fused MLP via bf16 MFMA + weightnet1 + k-sum ----------------
#define PPB 8
__device__ ALWAYS_INLINE bf16x8 load_wfrag(const float* __restrict__ Wg,
                                           int kbase, int col, int kmax) {
  bf16x8 r;
#pragma unroll
  for (int j = 0; j < 8; ++j) {
    int k = kbase + j;
    float f = (k < kmax) ? Wg[(size_t)k * 128 + col] : 0.f;
    r[j] = (short)bf16rne(f);
  }
  return r;
}

__global__ __launch_bounds__(512) void k_mlp_mfma(
    const float* __restrict__ p1t, const float* __restrict__ p2t,
    const float* __restrict__ x1t, const float* __restrict__ x2t,
    const int* __restrict__ kidx,
    const float* __restrict__ W1, const float* __restrict__ B1v,
    const float* __restrict__ W2, const float* __restrict__ B2v,
    const float* __restrict__ wnw1, const float* __restrict__ wnb1,
    const float* __restrict__ wnw2, const float* __restrict__ wnb2,
    const float* __restrict__ wnw3, const float* __restrict__ wnb3,
    float* __restrict__ ptp)
{
  __shared__ __align__(16) unsigned short sA1[16 * 168];
  __shared__ __align__(16) unsigned short sH1[16 * 136];
  __shared__ __align__(16) float s_wv[16 * 128];
  __shared__ __align__(16) float s_c1[24];
  __shared__ __align__(16) float s_cb1[8];
  __shared__ __align__(16) float s_c2[64];
  __shared__ __align__(16) float s_cb2[8];
  __shared__ __align__(16) float s_w3[1024];
  __shared__ __align__(16) float s_b3[128];
  int tid = threadIdx.x;
  int w = tid >> 6, lane = tid & 63;
  int col = (w << 4) + (lane & 15);
  int kr0 = (lane >> 4) * 8;
  if (tid < 24) s_c1[tid] = wnw1[tid];
  else if (tid < 32) s_cb1[tid - 24] = wnb1[tid - 24];
  else if (tid < 96) s_c2[tid - 32] = wnw2[tid - 32];
  else if (tid < 104) s_cb2[tid - 96] = wnb2[tid - 96];
  if (tid >= 128 && tid < 256) s_b3[tid - 128] = wnb3[tid - 128];
  for (int i = tid; i < 1024; i += 512) s_w3[i] = wnw3[i];
  bf16x8 w1f0 = load_wfrag(W1, 0 + kr0, col, 131);
  bf16x8 w1f1 = load_wfrag(W1, 32 + kr0, col, 131);
  bf16x8 w1f2 = load_wfrag(W1, 64 + kr0, col, 131);
  bf16x8 w1f3 = load_wfrag(W1, 96 + kr0, col, 131);
  bf16x8 w1f4 = load_wfrag(W1, 128 + kr0, col, 131);
  bf16x8 w2f0 = load_wfrag(W2, 0 + kr0, col, 128);
  bf16x8 w2f1 = load_wfrag(W2, 32 + kr0, col, 128);
  bf16x8 w2f2 = load_wfrag(W2, 64 + kr0, col, 128);
  bf16x8 w2f3 = load_wfrag(W2, 96 + kr0, col, 128);
  float b1c = B1v[col], b2c = B2v[col];
  int blk0 = blockIdx.x * PPB;
  int base = (blk0 >> 12) << 12;
  int r_st = tid >> 5, t_st = tid & 31;

  for (int p = 0; p < PPB; ++p) {
    int gid = blk0 + p;
    __syncthreads();
    {
      int m = kidx[(size_t)gid * 16 + r_st];
      int grow = base + m;
      float4 cx1 = *(const float4*)&x1t[(size_t)gid * 4];
      float4 cx2 = *(const float4*)&x2t[(size_t)grow * 4];
      unsigned short* row = &sA1[r_st * 168];
      row[t_st]      = bf16rne(p1t[(size_t)gid * 64 + t_st]);
      row[t_st + 32] = bf16rne(p1t[(size_t)gid * 64 + t_st + 32]);
      row[t_st + 64] = bf16rne(p2t[(size_t)grow * 64 + t_st]);
      row[t_st + 96] = bf16rne(p2t[(size_t)grow * 64 + t_st + 32]);
      float dx = cx2.x - cx1.x, dy = cx2.y - cx1.y, dz = cx2.z - cx1.z;
      float dv_ = (t_st == 0) ? dx : (t_st == 1) ? dy : (t_st == 2) ? dz : 0.f;
      row[t_st + 128] = bf16rne(dv_);
      float h1w0 = fmaxf(fmaf(dz, s_c1[16], fmaf(dy, s_c1[8],  fmaf(dx, s_c1[0], s_cb1[0]))), 0.f);
      float h1w1 = fmaxf(fmaf(dz, s_c1[17], fmaf(dy, s_c1[9],  fmaf(dx, s_c1[1], s_cb1[1]))), 0.f);
      float h1w2 = fmaxf(fmaf(dz, s_c1[18], fmaf(dy, s_c1[10], fmaf(dx, s_c1[2], s_cb1[2]))), 0.f);
      float h1w3 = fmaxf(fmaf(dz, s_c1[19], fmaf(dy, s_c1[11], fmaf(dx, s_c1[3], s_cb1[3]))), 0.f);
      float h1w4 = fmaxf(fmaf(dz, s_c1[20], fmaf(dy, s_c1[12], fmaf(dx, s_c1[4], s_cb1[4]))), 0.f);
      float h1w5 = fmaxf(fmaf(dz, s_c1[21], fmaf(dy, s_c1[13], fmaf(dx, s_c1[5], s_cb1[5]))), 0.f);
      float h1w6 = fmaxf(fmaf(dz, s_c1[22], fmaf(dy, s_c1[14], fmaf(dx, s_c1[6], s_cb1[6]))), 0.f);
      float h1w7 = fmaxf(fmaf(dz, s_c1[23], fmaf(dy, s_c1[15], fmaf(dx, s_c1[7], s_cb1[7]))), 0.f);
#define H2W(j) float h2w##j; { float a_ = s_cb2[j]; \
      a_ = fmaf(h1w0, s_c2[0 * 8 + j], a_); a_ = fmaf(h1w1, s_c2[1 * 8 + j], a_); \
      a_ = fmaf(h1w2, s_c2[2 * 8 + j], a_); a_ = fmaf(h1w3, s_c2[3 * 8 + j], a_); \
      a_ = fmaf(h1w4, s_c2[4 * 8 + j], a_); a_ = fmaf(h1w5, s_c2[5 * 8 + j], a_); \
      a_ = fmaf(h1w6, s_c2[6 * 8 + j], a_); a_ = fmaf(h1w7, s_c2[7 * 8 + j], a_); \
      h2w##j = fmaxf(a_, 0.f); }
      H2W(0) H2W(1) H2W(2) H2W(3) H2W(4) H2W(5) H2W(6) H2W(7)
#undef H2W
      int c4 = t_st * 4;
      float4 wv = *(const float4*)&s_b3[c4];
#define WV(j) { float4 w3 = *(const float4*)&s_w3[j * 128 + c4]; \
      wv.x = fmaf(h2w##j, w3.x, wv.x); wv.y = fmaf(h2w##j, w3.y, wv.y); \
      wv.z = fmaf(h2w##j, w3.z, wv.z); wv.w = fmaf(h2w##j, w3.w, wv.w); }
      WV(0) WV(1) WV(2) WV(3) WV(4) WV(5) WV(6) WV(7)
#undef WV
      wv.x = fmaxf(wv.x, 0.f); wv.y = fmaxf(wv.y, 0.f);
      wv.z = fmaxf(wv.z, 0.f); wv.w = fmaxf(wv.w, 0.f);
      *(float4*)&s_wv[r_st * 128 + c4] = wv;
    }
    __syncthreads();
    {
      int ab = (lane & 15) * 168 + kr0;
      f32x4 acc = {0.f, 0.f, 0.f, 0.f};
      acc = __builtin_amdgcn_mfma_f32_16x16x32_bf16(*(const bf16x8*)&sA1[ab],       w1f0, acc, 0, 0, 0);
      acc = __builtin_amdgcn_mfma_f32_16x16x32_bf16(*(const bf16x8*)&sA1[ab + 32],  w1f1, acc, 0, 0, 0);
      acc = __builtin_amdgcn_mfma_f32_16x16x32_bf16(*(const bf16x8*)&sA1[ab + 64],  w1f2, acc, 0, 0, 0);
      acc = __builtin_amdgcn_mfma_f32_16x16x32_bf16(*(const bf16x8*)&sA1[ab + 96],  w1f3, acc, 0, 0, 0);
      acc = __builtin_amdgcn_mfma_f32_16x16x32_bf16(*(const bf16x8*)&sA1[ab + 128], w1f4, acc, 0, 0, 0);
      int rw0 = (lane >> 4) * 4;
#pragma unroll
      for (int r = 0; r < 4; ++r)
        sH1[(rw0 + r) * 136 + col] = bf16rne(leakyf(acc[r] + b1c));
    }
    __syncthreads();
    {
      int ab = (lane & 15) * 136 + kr0;
      f32x4 acc = {0.f, 0.f, 0.f, 0.f};
      acc = __builtin_amdgcn_mfma_f32_16x16x32_bf16(*(const bf16x8*)&sH1[ab],      w2f0, acc, 0, 0, 0);
      acc = __builtin_amdgcn_mfma_f32_16x16x32_bf16(*(const bf16x8*)&sH1[ab + 32], w2f1, acc, 0, 0, 0);
      acc = __builtin_amdgcn_mfma_f32_16x16x32_bf16(*(const bf16x8*)&sH1[ab + 64], w2f2, acc, 0, 0, 0);
      acc = __builtin_amdgcn_mfma_f32_16x16x32_bf16(*(const bf16x8*)&sH1[ab + 96], w2f3, acc, 0, 0, 0);
      int rw0 = (lane >> 4) * 4;
      float v = 0.f;
#pragma unroll
      for (int r = 0; r < 4; ++r)
        v = fmaf(s_wv[(rw0 + r) * 128 + col], leakyf(acc[r] + b2c), v);
      v += __shfl_xor(v, 16);
      v += __shfl_xor(v, 32);
      if (lane < 16) ptp[(size_t)gid * 128 + col] = v;
    }
  }
}

// ---------------- final: weightnet2 + gather + k-sum + transpose store ----------------
__global__ __launch_bounds__(256) void k_final(
    const float* __restrict__ x1t, const int* __restrict__ idx2,
    const float* __restrict__ ptp,
    const float* __restrict__ wnw1, const float* __restrict__ wnb1,
    const float* __restrict__ wnw2, const float* __restrict__ wnb2,
    const float* __restrict__ wnw3, const float* __restrict__ wnb3,
    float* __restrict__ out0)
{
  __shared__ __align__(16) float s_gc[16][128];
  __shared__ __align__(16) float s_wn[16][8];
  __shared__ __align__(16) float s_red[2][128];
  int gid = blockIdx.x, b = gid >> 12, n = gid & (NPTS - 1);
  int tid = threadIdx.x;
  if (tid < 16) {
    int m = idx2[(size_t)gid * 16 + tid];
    float4 c2 = *(const float4*)&x1t[(size_t)((b << 12) + m) * 4];
    float4 c1 = *(const float4*)&x1t[(size_t)gid * 4];
    float dx = c2.x - c1.x, dy = c2.y - c1.y, dz = c2.z - c1.z;
    float h1w[8];
#pragma unroll
    for (int j = 0; j < 8; ++j)
      h1w[j] = fmaxf(fmaf(dz, wnw1[16 + j], fmaf(dy, wnw1[8 + j], fmaf(dx, wnw1[j], wnb1[j]))), 0.f);
#pragma unroll
    for (int j = 0; j < 8; ++j) {
      float a = wnb2[j];
#pragma unroll
      for (int qq = 0; qq < 8; ++qq) a = fmaf(h1w[qq], wnw2[qq * 8 + j], a);
      s_wn[tid][j] = fmaxf(a, 0.f);
    }
  }
  int k2 = tid >> 4, i2 = tid & 15;
  int mg = idx2[(size_t)gid * 16 + k2];
  const float* src = &ptp[(size_t)((b << 12) + mg) * 128 + i2 * 8];
  *(float4*)&s_gc[k2][i2 * 8] = *(const float4*)&src[0];
  *(float4*)&s_gc[k2][i2 * 8 + 4] = *(const float4*)&src[4];
  __syncthreads();
  int ch = tid & 127, kg2 = tid >> 7;
  float r = 0.f;
#pragma unroll
  for (int jj = 0; jj < 8; ++jj) {
    int k = kg2 * 8 + jj;
    float4 wa = *(const float4*)&s_wn[k][0];
    float4 wb = *(const float4*)&s_wn[k][4];
    float wv = wnb3[ch];
    wv = fmaf(wa.x, wnw3[ch], wv);
    wv = fmaf(wa.y, wnw3[128 + ch], wv);
    wv = fmaf(wa.z, wnw3[256 + ch], wv);
    wv = fmaf(wa.w, wnw3[384 + ch], wv);
    wv = fmaf(wb.x, wnw3[512 + ch], wv);
    wv = fmaf(wb.y, wnw3[640 + ch], wv);
    wv = fmaf(wb.z, wnw3[768 + ch], wv);
    wv = fmaf(wb.w, wnw3[896 + ch], wv);
    wv = fmaxf(wv, 0.f);
    r = fmaf(wv, s_gc[k][ch], r);
  }
  s_red[kg2][ch] = r;
  __syncthreads();
  if (tid < 128)
    out0[(size_t)(b * 128 + tid) * NPTS + n] = s_red[0][tid] + s_red[1][tid];
}

extern "C" void kernel_launch(void* const* d_in, const int* in_sizes, int n_in,
                              void* d_out, int out_size, void* d_ws, size_t ws_size,
                              hipStream_t stream) {
  (void)in_sizes; (void)n_in; (void)out_size; (void)ws_size;
  const float* xyz1   = (const float*)d_in[0];
  const float* xyz2   = (const float*)d_in[1];
  const float* pts1   = (const float*)d_in[2];
  const float* pts2   = (const float*)d_in[3];
  const float* vel1   = (const float*)d_in[4];
  const float* w_xyz  = (const float*)d_in[8];
  const float* w_pts  = (const float*)d_in[10];
  const float* mlp_w1 = (const float*)d_in[11];
  const float* mlp_b1 = (const float*)d_in[12];
  const float* mlp_w2 = (const float*)d_in[13];
  const float* mlp_b2 = (const float*)d_in[14];
  const float* wn1_w1 = (const float*)d_in[15];
  const float* wn1_b1 = (const float*)d_in[16];
  const float* wn1_w2 = (const float*)d_in[17];
  const float* wn1_b2 = (const float*)d_in[18];
  const float* wn1_w3 = (const float*)d_in[19];
  const float* wn1_b3 = (const float*)d_in[20];
  const float* wn2_w1 = (const float*)d_in[21];
  const float* wn2_b1 = (const float*)d_in[22];
  const float* wn2_w2 = (const float*)d_in[23];
  const float* wn2_b2 = (const float*)d_in[24];
  const float* wn2_w3 = (const float*)d_in[25];
  const float* wn2_b3 = (const float*)d_in[26];

  char* ws = (char*)d_ws;
  size_t off = 0;
  // pd (32 MB) serves three successive roles: [exact knn3 dists 0-8MB + aliased
  // pi ints 8-16MB, consumed by k_rigid], then knnf's 64-stream packed keys
  // (full 32MB), then knnv's 32-stream keys (first 16MB). Launch order makes
  // each handoff safe.
  float* pd   = (float*)(ws + off); off += (size_t)NQ * NPSF * 16 * 4;   // 32 MB
  int*   pi   = (int*)(pd + (size_t)NQ * NSEG3 * 8);                     // aliased @ +8MB
  unsigned short* f1b = (unsigned short*)(ws + off); off += (size_t)NQ * KB96 * 2;
  unsigned short* f2b = (unsigned short*)(ws + off); off += (size_t)NQ * KB96 * 2;
  float* n1   = (float*)(ws + off); off += (size_t)NQ * 4;
  float* n2a  = (float*)(ws + off); off += (size_t)NQ * 4;
  float* p1t  = (float*)(ws + off); off += (size_t)NQ * DD * 4;
  float* p2t  = (float*)(ws + off); off += (size_t)NQ * DD * 4;
  float* x1t  = (float*)(ws + off); off += (size_t)NQ * 4 * 4;
  float* x2t  = (float*)(ws + off); off += (size_t)NQ * 4 * 4;
  int*   kidx = (int*)(ws + off);   off += (size_t)NQ * KNN * 4;
  float* ptp  = (float*)(ws + off); off += (size_t)NQ * 128 * 4;
  int*   idx2 = (int*)(ws + off);   off += (size_t)NQ * KNN * 4;
  float* v4   = (float*)(ws + off); off += (size_t)NQ * 4 * 4;

  float* out0 = (float*)d_out;
  float* outv = (float*)d_out + VOFF;

  k_prep<<<256, 256, 0, stream>>>(xyz1, xyz2, pts1, pts2, w_xyz, w_pts,
                                  f1b, f2b, n1, n2a, p1t, p2t, x1t, x2t);
  k_knn3<<<dim3(32, NSEG3), 256, 0, stream>>>(x1t, pd, pi);
  k_rigid<<<128, 256, 0, stream>>>(pd, pi, x1t, vel1, outv, v4);
  k_knnf_mfma<<<dim3(NQ / 16, 4), 256, 0, stream>>>(f1b, f2b, n1, n2a, pd);
  k_mergepk<0><<<NQ / 32, 256, 0, stream>>>(pd, kidx);
  k_mlp_mfma<<<NQ / PPB, 512, 0, stream>>>(p1t, p2t, x1t, x2t, kidx,
                                           mlp_w1, mlp_b1, mlp_w2, mlp_b2,
                                           wn1_w1, wn1_b1, wn1_w2, wn1_b2,
                                           wn1_w3, wn1_b3, ptp);
  k_knnv<<<dim3(32, 32), 256, 0, stream>>>(v4, pd);
  k_mergepk<1><<<NQ / 64, 256, 0, stream>>>(pd, idx2);
  k_final<<<NQ, 256, 0, stream>>>(x1t, idx2, ptp,
                                  wn2_w1, wn2_b1, wn2_w2, wn2_b2, wn2_w3, wn2_b3, out0);
}

// Round 17
// 335.043 us; speedup vs baseline: 1.0496x; 1.0496x over previous
//
#include <hip/hip_runtime.h>

#define NPTS 4096
#define NQ   8192      // B*N
#define DD   64
#define KNN  16
#define KC   8
#define NSEG3 32       // exact knn3/rigid streams (seg length 128)
#define NPSEG 32       // psegs for packed knnf/knnv paths
#define KB96 96        // bf16 feature row: 67 real + 29 zeros
#define FSTR 104       // padded LDS row stride (shorts) = 13 float4 (odd -> no conflicts)
#define VOFF 1048576   // B*128*N, float offset of v_world in d_out

#define ALWAYS_INLINE __attribute__((always_inline)) inline

typedef __attribute__((ext_vector_type(8))) short bf16x8;
typedef __attribute__((ext_vector_type(4))) float f32x4;

__device__ ALWAYS_INLINE float leakyf(float x) { return x > 0.f ? x : 0.1f * x; }

__device__ ALWAYS_INLINE unsigned short bf16rne(float f) {
  unsigned u = __float_as_uint(f);
  u = (u + 0x7FFFu + ((u >> 16) & 1u)) >> 16;
  return (unsigned short)u;
}

// Pack distance + 12-bit tag into one f32 sort key (d>=0 so float cmp == uint cmp).
__device__ ALWAYS_INLINE float packdt(float d, unsigned tag12) {
  return __uint_as_float((__float_as_uint(d) & 0xFFFFF000u) | tag12);
}

// ---- top-k state as NAMED SCALARS (never arrays — hipcc scratch-allocates
// per-thread arrays: rounds 1-4 measured 5-10x slowdown from this) ----
#define TK8_FOREACH(M)  M(0) M(1) M(2) M(3) M(4) M(5) M(6) M(7)
#define TK16_FOREACH(M) M(0) M(1) M(2) M(3) M(4) M(5) M(6) M(7) \
                        M(8) M(9) M(10) M(11) M(12) M(13) M(14) M(15)

#define TK_DECL1(i) float tkd##i = 3.4e38f; int tki##i = 0;
#define TK_STEP1(i) { bool c = vd < tkd##i; float t_ = tkd##i; int u_ = tki##i; \
                      tkd##i = c ? vd : tkd##i; tki##i = c ? vi : tki##i; \
                      vd = c ? t_ : vd; vi = c ? u_ : vi; }
#define TK8_DECL  TK8_FOREACH(TK_DECL1)
#define TK8_INS(dexp, mexp)  { float vd = (dexp); int vi = (mexp); \
                               if (vd < tkd7)  { TK8_FOREACH(TK_STEP1) } }
#define TK8_RESET1(i) tkd##i = 3.4e38f; tki##i = 0;

#define PK_DECL1(i) float pk##i = __uint_as_float(0x7F7FFFFFu);
#define PK_RESET1(i) pk##i = __uint_as_float(0x7F7FFFFFu);
#define PK_STEP1(i) { float lo_ = fminf(pk##i, pv); pv = fmaxf(pk##i, pv); pk##i = lo_; }
#define PK16_DECL    TK16_FOREACH(PK_DECL1)
#define PK16_INS(ve) { float pv = (ve); TK16_FOREACH(PK_STEP1) }
#define PK_STORE1(i) pdq[i] = pk##i;
#define PK16_STORE   TK16_FOREACH(PK_STORE1)

// ------- prep: 64 points x 4 channel-parts per block (256 blocks, 2 clouds) -------
__global__ __launch_bounds__(256) void k_prep(
    const float* __restrict__ xyz1, const float* __restrict__ xyz2,
    const float* __restrict__ pts1, const float* __restrict__ pts2,
    const float* __restrict__ w_xyz_p, const float* __restrict__ w_points_p,
    unsigned short* __restrict__ f1b, unsigned short* __restrict__ f2b,
    float* __restrict__ n1, float* __restrict__ n2a,
    float* __restrict__ p1t, float* __restrict__ p2t,
    float* __restrict__ x1t, float* __restrict__ x2t)
{
  __shared__ float s_acc[64][5];
  int tid = threadIdx.x;
  int nl = tid & 63, part = tid >> 6;
  int cloud = blockIdx.x >> 7;
  int gid = ((blockIdx.x & 127) << 6) + nl;
  int b = gid >> 12, n = gid & (NPTS - 1);
  float wx = w_xyz_p[0], wp = w_points_p[0];
  const float* xyz = cloud ? xyz2 : xyz1;
  const float* pts = cloud ? pts2 : pts1;
  unsigned short* fb = cloud ? f2b : f1b;
  float* nrm = cloud ? n2a : n1;
  float* pt  = cloud ? p2t : p1t;
  float* xt  = cloud ? x2t : x1t;
  const float* pb = pts + (size_t)b * DD * NPTS;
  float* pr = pt + (size_t)gid * DD;
  unsigned short* fr = fb + (size_t)gid * KB96;
  int c0 = part * 16;
  float acc = 0.f;
#pragma unroll 4
  for (int j = 0; j < 16; ++j) {
    float v = pb[(size_t)(c0 + j) * NPTS + n];
    pr[c0 + j] = v;
    float fv = wp * v;
    fr[3 + c0 + j] = bf16rne(fv);
    acc = fmaf(fv, fv, acc);
  }
  s_acc[nl][part] = acc;
  if (part == 1) { for (int c = 67; c < 82; ++c) fr[c] = 0; }
  else if (part == 2) { for (int c = 82; c < KB96; ++c) fr[c] = 0; }
  __syncthreads();
  if (part == 0) {
    const float* xb = xyz + (size_t)b * 3 * NPTS;
    float x = xb[n], y = xb[NPTS + n], z = xb[2 * NPTS + n];
    float nrm2 = fmaf(z, z, fmaf(y, y, x * x));
    float4 xv; xv.x = x; xv.y = y; xv.z = z; xv.w = nrm2;
    *(float4*)&xt[(size_t)gid * 4] = xv;
    float fx = wx * x, fy = wx * y, fz = wx * z;
    fr[0] = bf16rne(fx); fr[1] = bf16rne(fy); fr[2] = bf16rne(fz);
    float a = fmaf(fz, fz, fmaf(fy, fy, fx * fx));
    a += s_acc[nl][0] + s_acc[nl][1] + s_acc[nl][2] + s_acc[nl][3];
    nrm[gid] = a;
  }
}

// ------- knn over xyz1, 32 segs x 128 candidates, K=8 EXACT (feeds rigid) -------
__global__ __launch_bounds__(256) void k_knn3(
    const float* __restrict__ x4, float* __restrict__ pd, int* __restrict__ pi)
{
  __shared__ __align__(16) float4 sc[128];
  int seg = blockIdx.y;                       // 0..31
  int Q = blockIdx.x * 256 + threadIdx.x;
  int b = Q >> 12;
  float4 q = *(const float4*)&x4[(size_t)Q * 4];
  TK8_DECL
  int gbase = (b << 12) + seg * 128;
  if (threadIdx.x < 128)
    sc[threadIdx.x] = *(const float4*)&x4[(size_t)(gbase + threadIdx.x) * 4];
  __syncthreads();
  int m0 = seg * 128;
#pragma unroll
  for (int j = 0; j < 128; ++j) {
    float4 c = sc[j];
    float dot = fmaf(q.z, c.z, fmaf(q.y, c.y, q.x * c.x));
    float d = fmaxf(q.w + c.w - 2.f * dot, 0.f);
    TK8_INS(d, m0 + j)
  }
  float* pdq = pd + ((size_t)Q * NSEG3 + seg) * 8;
  int* piq = pi + ((size_t)Q * NSEG3 + seg) * 8;
#define ST8(i) pdq[i] = tkd##i; piq[i] = tki##i;
  TK8_FOREACH(ST8)
#undef ST8
}

// ------- knn over v_world, 32 segs x 128 candidates, packed keys -------
__global__ __launch_bounds__(256) void k_knnv(
    const float* __restrict__ x4, float* __restrict__ pd)
{
  __shared__ __align__(16) float4 sc[128];
  int seg = blockIdx.y;                      // 0..31
  int Q = blockIdx.x * 256 + threadIdx.x;
  int b = Q >> 12;
  float4 q = *(const float4*)&x4[(size_t)Q * 4];
  PK16_DECL
  int gbase = (b << 12) + seg * 128;
  if (threadIdx.x < 128)
    sc[threadIdx.x] = *(const float4*)&x4[(size_t)(gbase + threadIdx.x) * 4];
  __syncthreads();
#pragma unroll
  for (int j = 0; j < 128; ++j) {
    float4 c = sc[j];
    float dot = fmaf(q.z, c.z, fmaf(q.y, c.y, q.x * c.x));
    float d = fmaxf(q.w + c.w - 2.f * dot, 0.f);
    PK16_INS(packdt(d, ((unsigned)j << 5) | (unsigned)seg))
  }
  float* pdq = pd + ((size_t)Q * NPSEG + seg) * 16;
  PK16_STORE
}

// ------- merge 32x8 exact (4 threads/query) + rigid velocity regression -------
__global__ __launch_bounds__(256) void k_rigid(
    const float* __restrict__ pd, const int* __restrict__ pi,
    const float* __restrict__ x4, const float* __restrict__ vel1,
    float* __restrict__ vout, float* __restrict__ v4out)
{
  __shared__ __align__(16) float s_d[64][33];
  __shared__ __align__(16) int   s_i[64][33];
  int tid = threadIdx.x;
  int ql = tid >> 2, part = tid & 3;
  int Q = blockIdx.x * 64 + ql;
  int b = Q >> 12;
  TK8_DECL
  {
    int s0 = part * 8;
    const float* pbase = pd + ((size_t)Q * NSEG3 + s0) * 8;
    const int* ibase = pi + ((size_t)Q * NSEG3 + s0) * 8;
#pragma unroll
    for (int s = 0; s < 8; ++s) {
#pragma unroll
      for (int j = 0; j < 8; ++j) TK8_INS(pbase[s * 8 + j], ibase[s * 8 + j])
    }
  }
#define STP(i) s_d[ql][part * 8 + i] = tkd##i; s_i[ql][part * 8 + i] = tki##i;
  TK8_FOREACH(STP)
#undef STP
  __syncthreads();
  if (part != 0) return;
  TK8_FOREACH(TK8_RESET1)
#pragma unroll
  for (int j = 0; j < 32; ++j) TK8_INS(s_d[ql][j], s_i[ql][j])
  int base = b << 12;
  double a00 = 0, a01 = 0, a02 = 0, a11 = 0, a12 = 0, a22 = 0;
  double r0 = 0, r1 = 0, r2 = 0;
#define RIG_ACC(i) { \
    float4 c = *(const float4*)&x4[(size_t)(base + tki##i) * 4]; \
    float nr = sqrtf(c.w); \
    float ux = c.x / nr, uy = c.y / nr, uz = c.z / nr; \
    float cv = vel1[base + tki##i]; \
    double dx = ux, dy = uy, dz = uz, dvv = cv; \
    a00 += dx * dx; a01 += dx * dy; a02 += dx * dz; \
    a11 += dy * dy; a12 += dy * dz; a22 += dz * dz; \
    r0 += dx * dvv; r1 += dy * dvv; r2 += dz * dvv; }
  TK8_FOREACH(RIG_ACC)
#undef RIG_ACC
  a00 += 1e-6; a11 += 1e-6; a22 += 1e-6;
  double c00 = a11 * a22 - a12 * a12;
  double c01 = a02 * a12 - a01 * a22;
  double c02 = a01 * a12 - a02 * a11;
  double c11 = a00 * a22 - a02 * a02;
  double c12 = a02 * a01 - a00 * a12;
  double c22 = a00 * a11 - a01 * a01;
  double det = a00 * c00 + a01 * c01 + a02 * c02;
  double inv = 1.0 / det;
  float vx = (float)((c00 * r0 + c01 * r1 + c02 * r2) * inv);
  float vy = (float)((c01 * r0 + c11 * r1 + c12 * r2) * inv);
  float vz = (float)((c02 * r0 + c12 * r1 + c22 * r2) * inv);
  vout[(size_t)Q * 3 + 0] = vx;
  vout[(size_t)Q * 3 + 1] = vy;
  vout[(size_t)Q * 3 + 2] = vz;
  float4 v; v.x = vx; v.y = vy; v.z = vz;
  v.w = fmaf(vz, vz, fmaf(vy, vy, vx * vx));
  *(float4*)&v4out[(size_t)Q * 4] = v;
}

// ------- knnf via bf16 MFMA, double-buffered: 16 queries x 2048 cands/block -------
__global__ __launch_bounds__(256) void k_knnf_mfma(
    const unsigned short* __restrict__ f1b, const unsigned short* __restrict__ f2b,
    const float* __restrict__ n1, const float* __restrict__ n2a,
    float* __restrict__ pd)
{
  __shared__ __align__(16) unsigned short sf1[16 * FSTR];
  __shared__ __align__(16) unsigned short sf2[2][64 * FSTR];
  __shared__ __align__(16) float sn1[16];
  __shared__ __align__(16) float sn2[2][64];
  __shared__ __align__(16) float sD[64][17];
  int tid = threadIdx.x;
  int w = tid >> 6, lane = tid & 63;
  int i15 = lane & 15, g = lane >> 4, kr0 = g * 8;
  int blockq = blockIdx.x * 16;
  int b = blockq >> 12;
  int seg = blockIdx.y;                       // 0..1 (2048 candidates each)
  int gbase = (b << 12) + seg * 2048;
  {
    const float4* src = (const float4*)(f1b + (size_t)blockq * KB96);
    if (tid < 192) ((float4*)sf1)[tid + tid / 12] = src[tid];   // 12 f4/row -> stride 13
    if (tid < 16) sn1[tid] = n1[blockq + tid];
  }
  {   // prologue: stage chunk 0 into buffer 0
    const float4* src = (const float4*)(f2b + (size_t)gbase * KB96);
    int i0 = tid, i1 = tid + 256, i2 = tid + 512;
    ((float4*)sf2[0])[i0 + i0 / 12] = src[i0];
    ((float4*)sf2[0])[i1 + i1 / 12] = src[i1];
    ((float4*)sf2[0])[i2 + i2 / 12] = src[i2];
    if (tid < 64) sn2[0][tid] = n2a[gbase + tid];
  }
  __syncthreads();
  bf16x8 af0 = *(const bf16x8*)&sf1[i15 * FSTR + kr0];
  bf16x8 af1 = *(const bf16x8*)&sf1[i15 * FSTR + 32 + kr0];
  bf16x8 af2 = *(const bf16x8*)&sf1[i15 * FSTR + 64 + kr0];
  float nq0 = sn1[g * 4 + 0], nq1 = sn1[g * 4 + 1];
  float nq2 = sn1[g * 4 + 2], nq3 = sn1[g * 4 + 3];
  PK16_DECL
  int q_tk = tid & 15, p_tk = tid >> 4;       // 16 queries x 16 p-streams
  for (int ch = 0; ch < 32; ++ch) {
    int cur = ch & 1;
    {   // MFMA + pack -> sD (reads sf2[cur])
      int crow = w * 16 + i15;
      const unsigned short* c_ = &sf2[cur][crow * FSTR + kr0];
      f32x4 acc = {0.f, 0.f, 0.f, 0.f};
      acc = __builtin_amdgcn_mfma_f32_16x16x32_bf16(af0, *(const bf16x8*)&c_[0],  acc, 0, 0, 0);
      acc = __builtin_amdgcn_mfma_f32_16x16x32_bf16(af1, *(const bf16x8*)&c_[32], acc, 0, 0, 0);
      acc = __builtin_amdgcn_mfma_f32_16x16x32_bf16(af2, *(const bf16x8*)&c_[64], acc, 0, 0, 0);
      float nn2 = sn2[cur][crow];
      unsigned tag = (((unsigned)(ch * 4 + (crow & 3))) << 5) |
                     (unsigned)(seg * 16 + (crow >> 2));
      sD[crow][g * 4 + 0] = packdt(fmaxf(nq0 + nn2 - 2.f * acc[0], 0.f), tag);
      sD[crow][g * 4 + 1] = packdt(fmaxf(nq1 + nn2 - 2.f * acc[1], 0.f), tag);
      sD[crow][g * 4 + 2] = packdt(fmaxf(nq2 + nn2 - 2.f * acc[2], 0.f), tag);
      sD[crow][g * 4 + 3] = packdt(fmaxf(nq3 + nn2 - 2.f * acc[3], 0.f), tag);
    }
    __syncthreads();   // sD ready; all reads of sf2[cur] complete
    if (ch + 1 < 32) {   // stage next chunk into the other buffer (overlaps top-k)
      const float4* src = (const float4*)(f2b + (size_t)(gbase + (ch + 1) * 64) * KB96);
      int i0 = tid, i1 = tid + 256, i2 = tid + 512;
      ((float4*)sf2[cur ^ 1])[i0 + i0 / 12] = src[i0];
      ((float4*)sf2[cur ^ 1])[i1 + i1 / 12] = src[i1];
      ((float4*)sf2[cur ^ 1])[i2 + i2 / 12] = src[i2];
      if (tid < 64) sn2[cur ^ 1][tid] = n2a[gbase + (ch + 1) * 64 + tid];
    }
#pragma unroll
    for (int j = 0; j < 4; ++j)
      PK16_INS(sD[p_tk * 4 + j][q_tk])
    __syncthreads();   // stage done + top-k reads of sD done
  }
  int pseg = seg * 16 + p_tk;
  float* pdq = pd + ((size_t)(blockq + q_tk) * NPSEG + pseg) * 16;
  PK16_STORE
}

// ------- packed merges (4 threads/query): 32 sorted psegs -> top-16 -------
// MODE 0 (knnf): m = (pseg>>4)*2048 + (local>>2)*64 + (pseg&15)*4 + (local&3)
// MODE 1 (knnv): m = pseg*128 + local
template<int MODE>
__global__ __launch_bounds__(256) void k_mergepk(
    const float* __restrict__ pd, int* __restrict__ oidx)
{
  __shared__ __align__(16) float s_k[64][65];
  int tid = threadIdx.x;
  int ql = tid >> 2, part = tid & 3;
  int Q = blockIdx.x * 64 + ql;
  PK16_DECL
  {
    const float* pbase = pd + ((size_t)Q * NPSEG + part * 8) * 16;
#pragma unroll
    for (int s = 0; s < 8; ++s) {
      for (int j = 0; j < 16; ++j) {     // sorted ascending -> per-thread break exact
        float v = pbase[s * 16 + j];
        if (!(v < pk15)) break;
        PK16_INS(v)
      }
    }
  }
#define STK(i) s_k[ql][part * 16 + i] = pk##i;
  TK16_FOREACH(STK)
#undef STK
  __syncthreads();
  if (part != 0) return;
  TK16_FOREACH(PK_RESET1)
#pragma unroll
  for (int p = 0; p < 4; ++p) {
    for (int j = 0; j < 16; ++j) {
      float v = s_k[ql][p * 16 + j];
      if (!(v < pk15)) break;
      PK16_INS(v)
    }
  }
#define DEC(i) { unsigned u = __float_as_uint(pk##i); int m_; \
    unsigned ps = u & 31u, lo = (u >> 5) & 127u; \
    if (MODE == 0) m_ = (int)(((ps >> 4) << 11) + ((lo >> 2) << 6) + ((ps & 15u) << 2) + (lo & 3u)); \
    else m_ = (int)((ps << 7) + lo); \
    oidx[(size_t)Q * KNN + i] = m_; }
  TK16_FOREACH(DEC)
#undef DEC
}

// ---------------- fused MLP via bf16 MFMA + weightnet1 + k-sum ----------------
#define PPB 8
__device__ ALWAYS_INLINE bf16x8 load_wfrag(const float* __restrict__ Wg,
                                           int kbase, int col, int kmax) {
  bf16x8 r;
#pragma unroll
  for (int j = 0; j < 8; ++j) {
    int k = kbase + j;
    float f = (k < kmax) ? Wg[(size_t)k * 128 + col] : 0.f;
    r[j] = (short)bf16rne(f);
  }
  return r;
}

__global__ __launch_bounds__(512) void k_mlp_mfma(
    const float* __restrict__ p1t, const float* __restrict__ p2t,
    const float* __restrict__ x1t, const float* __restrict__ x2t,
    const int* __restrict__ kidx,
    const float* __restrict__ W1, const float* __restrict__ B1v,
    const float* __restrict__ W2, const float* __restrict__ B2v,
    const float* __restrict__ wnw1, const float* __restrict__ wnb1,
    const float* __restrict__ wnw2, const float* __restrict__ wnb2,
    const float* __restrict__ wnw3, const float* __restrict__ wnb3,
    float* __restrict__ ptp)
{
  __shared__ __align__(16) unsigned short sA1[16 * 168];
  __shared__ __align__(16) unsigned short sH1[16 * 136];
  __shared__ __align__(16) float s_wv[16 * 128];
  __shared__ __align__(16) float s_c1[24];
  __shared__ __align__(16) float s_cb1[8];
  __shared__ __align__(16) float s_c2[64];
  __shared__ __align__(16) float s_cb2[8];
  __shared__ __align__(16) float s_w3[1024];
  __shared__ __align__(16) float s_b3[128];
  int tid = threadIdx.x;
  int w = tid >> 6, lane = tid & 63;
  int col = (w << 4) + (lane & 15);
  int kr0 = (lane >> 4) * 8;
  if (tid < 24) s_c1[tid] = wnw1[tid];
  else if (tid < 32) s_cb1[tid - 24] = wnb1[tid - 24];
  else if (tid < 96) s_c2[tid - 32] = wnw2[tid - 32];
  else if (tid < 104) s_cb2[tid - 96] = wnb2[tid - 96];
  if (tid >= 128 && tid < 256) s_b3[tid - 128] = wnb3[tid - 128];
  for (int i = tid; i < 1024; i += 512) s_w3[i] = wnw3[i];
  bf16x8 w1f0 = load_wfrag(W1, 0 + kr0, col, 131);
  bf16x8 w1f1 = load_wfrag(W1, 32 + kr0, col, 131);
  bf16x8 w1f2 = load_wfrag(W1, 64 + kr0, col, 131);
  bf16x8 w1f3 = load_wfrag(W1, 96 + kr0, col, 131);
  bf16x8 w1f4 = load_wfrag(W1, 128 + kr0, col, 131);
  bf16x8 w2f0 = load_wfrag(W2, 0 + kr0, col, 128);
  bf16x8 w2f1 = load_wfrag(W2, 32 + kr0, col, 128);
  bf16x8 w2f2 = load_wfrag(W2, 64 + kr0, col, 128);
  bf16x8 w2f3 = load_wfrag(W2, 96 + kr0, col, 128);
  float b1c = B1v[col], b2c = B2v[col];
  int blk0 = blockIdx.x * PPB;
  int base = (blk0 >> 12) << 12;
  int r_st = tid >> 5, t_st = tid & 31;

  for (int p = 0; p < PPB; ++p) {
    int gid = blk0 + p;
    __syncthreads();
    {
      int m = kidx[(size_t)gid * 16 + r_st];
      int grow = base + m;
      float4 cx1 = *(const float4*)&x1t[(size_t)gid * 4];
      float4 cx2 = *(const float4*)&x2t[(size_t)grow * 4];
      unsigned short* row = &sA1[r_st * 168];
      row[t_st]      = bf16rne(p1t[(size_t)gid * 64 + t_st]);
      row[t_st + 32] = bf16rne(p1t[(size_t)gid * 64 + t_st + 32]);
      row[t_st + 64] = bf16rne(p2t[(size_t)grow * 64 + t_st]);
      row[t_st + 96] = bf16rne(p2t[(size_t)grow * 64 + t_st + 32]);
      float dx = cx2.x - cx1.x, dy = cx2.y - cx1.y, dz = cx2.z - cx1.z;
      float dv_ = (t_st == 0) ? dx : (t_st == 1) ? dy : (t_st == 2) ? dz : 0.f;
      row[t_st + 128] = bf16rne(dv_);
      float h1w0 = fmaxf(fmaf(dz, s_c1[16], fmaf(dy, s_c1[8],  fmaf(dx, s_c1[0], s_cb1[0]))), 0.f);
      float h1w1 = fmaxf(fmaf(dz, s_c1[17], fmaf(dy, s_c1[9],  fmaf(dx, s_c1[1], s_cb1[1]))), 0.f);
      float h1w2 = fmaxf(fmaf(dz, s_c1[18], fmaf(dy, s_c1[10], fmaf(dx, s_c1[2], s_cb1[2]))), 0.f);
      float h1w3 = fmaxf(fmaf(dz, s_c1[19], fmaf(dy, s_c1[11], fmaf(dx, s_c1[3], s_cb1[3]))), 0.f);
      float h1w4 = fmaxf(fmaf(dz, s_c1[20], fmaf(dy, s_c1[12], fmaf(dx, s_c1[4], s_cb1[4]))), 0.f);
      float h1w5 = fmaxf(fmaf(dz, s_c1[21], fmaf(dy, s_c1[13], fmaf(dx, s_c1[5], s_cb1[5]))), 0.f);
      float h1w6 = fmaxf(fmaf(dz, s_c1[22], fmaf(dy, s_c1[14], fmaf(dx, s_c1[6], s_cb1[6]))), 0.f);
      float h1w7 = fmaxf(fmaf(dz, s_c1[23], fmaf(dy, s_c1[15], fmaf(dx, s_c1[7], s_cb1[7]))), 0.f);
#define H2W(j) float h2w##j; { float a_ = s_cb2[j]; \
      a_ = fmaf(h1w0, s_c2[0 * 8 + j], a_); a_ = fmaf(h1w1, s_c2[1 * 8 + j], a_); \
      a_ = fmaf(h1w2, s_c2[2 * 8 + j], a_); a_ = fmaf(h1w3, s_c2[3 * 8 + j], a_); \
      a_ = fmaf(h1w4, s_c2[4 * 8 + j], a_); a_ = fmaf(h1w5, s_c2[5 * 8 + j], a_); \
      a_ = fmaf(h1w6, s_c2[6 * 8 + j], a_); a_ = fmaf(h1w7, s_c2[7 * 8 + j], a_); \
      h2w##j = fmaxf(a_, 0.f); }
      H2W(0) H2W(1) H2W(2) H2W(3) H2W(4) H2W(5) H2W(6) H2W(7)
#undef H2W
      int c4 = t_st * 4;
      float4 wv = *(const float4*)&s_b3[c4];
#define WV(j) { float4 w3 = *(const float4*)&s_w3[j * 128 + c4]; \
      wv.x = fmaf(h2w##j, w3.x, wv.x); wv.y = fmaf(h2w##j, w3.y, wv.y); \
      wv.z = fmaf(h2w##j, w3.z, wv.z); wv.w = fmaf(h2w##j, w3.w, wv.w); }
      WV(0) WV(1) WV(2) WV(3) WV(4) WV(5) WV(6) WV(7)
#undef WV
      wv.x = fmaxf(wv.x, 0.f); wv.y = fmaxf(wv.y, 0.f);
      wv.z = fmaxf(wv.z, 0.f); wv.w = fmaxf(wv.w, 0.f);
      *(float4*)&s_wv[r_st * 128 + c4] = wv;
    }
    __syncthreads();
    {
      int ab = (lane & 15) * 168 + kr0;
      f32x4 acc = {0.f, 0.f, 0.f, 0.f};
      acc = __builtin_amdgcn_mfma_f32_16x16x32_bf16(*(const bf16x8*)&sA1[ab],       w1f0, acc, 0, 0, 0);
      acc = __builtin_amdgcn_mfma_f32_16x16x32_bf16(*(const bf16x8*)&sA1[ab + 32],  w1f1, acc, 0, 0, 0);
      acc = __builtin_amdgcn_mfma_f32_16x16x32_bf16(*(const bf16x8*)&sA1[ab + 64],  w1f2, acc, 0, 0, 0);
      acc = __builtin_amdgcn_mfma_f32_16x16x32_bf16(*(const bf16x8*)&sA1[ab + 96],  w1f3, acc, 0, 0, 0);
      acc = __builtin_amdgcn_mfma_f32_16x16x32_bf16(*(const bf16x8*)&sA1[ab + 128], w1f4, acc, 0, 0, 0);
      int rw0 = (lane >> 4) * 4;
#pragma unroll
      for (int r = 0; r < 4; ++r)
        sH1[(rw0 + r) * 136 + col] = bf16rne(leakyf(acc[r] + b1c));
    }
    __syncthreads();
    {
      int ab = (lane & 15) * 136 + kr0;
      f32x4 acc = {0.f, 0.f, 0.f, 0.f};
      acc = __builtin_amdgcn_mfma_f32_16x16x32_bf16(*(const bf16x8*)&sH1[ab],      w2f0, acc, 0, 0, 0);
      acc = __builtin_amdgcn_mfma_f32_16x16x32_bf16(*(const bf16x8*)&sH1[ab + 32], w2f1, acc, 0, 0, 0);
      acc = __builtin_amdgcn_mfma_f32_16x16x32_bf16(*(const bf16x8*)&sH1[ab + 64], w2f2, acc, 0, 0, 0);
      acc = __builtin_amdgcn_mfma_f32_16x16x32_bf16(*(const bf16x8*)&sH1[ab + 96], w2f3, acc, 0, 0, 0);
      int rw0 = (lane >> 4) * 4;
      float v = 0.f;
#pragma unroll
      for (int r = 0; r < 4; ++r)
        v = fmaf(s_wv[(rw0 + r) * 128 + col], leakyf(acc[r] + b2c), v);
      v += __shfl_xor(v, 16);
      v += __shfl_xor(v, 32);
      if (lane < 16) ptp[(size_t)gid * 128 + col] = v;
    }
  }
}

// ---------------- final: weightnet2 + gather + k-sum + transpose store ----------------
__global__ __launch_bounds__(256) void k_final(
    const float* __restrict__ x1t, const int* __restrict__ idx2,
    const float* __restrict__ ptp,
    const float* __restrict__ wnw1, const float* __restrict__ wnb1,
    const float* __restrict__ wnw2, const float* __restrict__ wnb2,
    const float* __restrict__ wnw3, const float* __restrict__ wnb3,
    float* __restrict__ out0)
{
  __shared__ __align__(16) float s_gc[16][128];
  __shared__ __align__(16) float s_wn[16][8];
  __shared__ __align__(16) float s_red[2][128];
  int gid = blockIdx.x, b = gid >> 12, n = gid & (NPTS - 1);
  int tid = threadIdx.x;
  if (tid < 16) {
    int m = idx2[(size_t)gid * 16 + tid];
    float4 c2 = *(const float4*)&x1t[(size_t)((b << 12) + m) * 4];
    float4 c1 = *(const float4*)&x1t[(size_t)gid * 4];
    float dx = c2.x - c1.x, dy = c2.y - c1.y, dz = c2.z - c1.z;
    float h1w[8];
#pragma unroll
    for (int j = 0; j < 8; ++j)
      h1w[j] = fmaxf(fmaf(dz, wnw1[16 + j], fmaf(dy, wnw1[8 + j], fmaf(dx, wnw1[j], wnb1[j]))), 0.f);
#pragma unroll
    for (int j = 0; j < 8; ++j) {
      float a = wnb2[j];
#pragma unroll
      for (int qq = 0; qq < 8; ++qq) a = fmaf(h1w[qq], wnw2[qq * 8 + j], a);
      s_wn[tid][j] = fmaxf(a, 0.f);
    }
  }
  int k2 = tid >> 4, i2 = tid & 15;
  int mg = idx2[(size_t)gid * 16 + k2];
  const float* src = &ptp[(size_t)((b << 12) + mg) * 128 + i2 * 8];
  *(float4*)&s_gc[k2][i2 * 8] = *(const float4*)&src[0];
  *(float4*)&s_gc[k2][i2 * 8 + 4] = *(const float4*)&src[4];
  __syncthreads();
  int ch = tid & 127, kg2 = tid >> 7;
  float r = 0.f;
#pragma unroll
  for (int jj = 0; jj < 8; ++jj) {
    int k = kg2 * 8 + jj;
    float4 wa = *(const float4*)&s_wn[k][0];
    float4 wb = *(const float4*)&s_wn[k][4];
    float wv = wnb3[ch];
    wv = fmaf(wa.x, wnw3[ch], wv);
    wv = fmaf(wa.y, wnw3[128 + ch], wv);
    wv = fmaf(wa.z, wnw3[256 + ch], wv);
    wv = fmaf(wa.w, wnw3[384 + ch], wv);
    wv = fmaf(wb.x, wnw3[512 + ch], wv);
    wv = fmaf(wb.y, wnw3[640 + ch], wv);
    wv = fmaf(wb.z, wnw3[768 + ch], wv);
    wv = fmaf(wb.w, wnw3[896 + ch], wv);
    wv = fmaxf(wv, 0.f);
    r = fmaf(wv, s_gc[k][ch], r);
  }
  s_red[kg2][ch] = r;
  __syncthreads();
  if (tid < 128)
    out0[(size_t)(b * 128 + tid) * NPTS + n] = s_red[0][tid] + s_red[1][tid];
}

extern "C" void kernel_launch(void* const* d_in, const int* in_sizes, int n_in,
                              void* d_out, int out_size, void* d_ws, size_t ws_size,
                              hipStream_t stream) {
  (void)in_sizes; (void)n_in; (void)out_size; (void)ws_size;
  const float* xyz1   = (const float*)d_in[0];
  const float* xyz2   = (const float*)d_in[1];
  const float* pts1   = (const float*)d_in[2];
  const float* pts2   = (const float*)d_in[3];
  const float* vel1   = (const float*)d_in[4];
  const float* w_xyz  = (const float*)d_in[8];
  const float* w_pts  = (const float*)d_in[10];
  const float* mlp_w1 = (const float*)d_in[11];
  const float* mlp_b1 = (const float*)d_in[12];
  const float* mlp_w2 = (const float*)d_in[13];
  const float* mlp_b2 = (const float*)d_in[14];
  const float* wn1_w1 = (const float*)d_in[15];
  const float* wn1_b1 = (const float*)d_in[16];
  const float* wn1_w2 = (const float*)d_in[17];
  const float* wn1_b2 = (const float*)d_in[18];
  const float* wn1_w3 = (const float*)d_in[19];
  const float* wn1_b3 = (const float*)d_in[20];
  const float* wn2_w1 = (const float*)d_in[21];
  const float* wn2_b1 = (const float*)d_in[22];
  const float* wn2_w2 = (const float*)d_in[23];
  const float* wn2_b2 = (const float*)d_in[24];
  const float* wn2_w3 = (const float*)d_in[25];
  const float* wn2_b3 = (const float*)d_in[26];

  char* ws = (char*)d_ws;
  size_t off = 0;
  // pd doubles as: exact knn3 distances (8 MB head, consumed by k_rigid BEFORE
  // k_knnf_mfma overwrites) and packed 32-stream keys (16 MB).
  float* pd   = (float*)(ws + off); off += (size_t)NQ * NPSEG * 16 * 4;  // 16 MB
  int*   pi   = (int*)(ws + off);   off += (size_t)NQ * NSEG3 * 8 * 4;   // 8 MB exact indices
  unsigned short* f1b = (unsigned short*)(ws + off); off += (size_t)NQ * KB96 * 2;
  unsigned short* f2b = (unsigned short*)(ws + off); off += (size_t)NQ * KB96 * 2;
  float* n1   = (float*)(ws + off); off += (size_t)NQ * 4;
  float* n2a  = (float*)(ws + off); off += (size_t)NQ * 4;
  float* p1t  = (float*)(ws + off); off += (size_t)NQ * DD * 4;
  float* p2t  = (float*)(ws + off); off += (size_t)NQ * DD * 4;
  float* x1t  = (float*)(ws + off); off += (size_t)NQ * 4 * 4;
  float* x2t  = (float*)(ws + off); off += (size_t)NQ * 4 * 4;
  int*   kidx = (int*)(ws + off);   off += (size_t)NQ * KNN * 4;
  float* ptp  = (float*)(ws + off); off += (size_t)NQ * 128 * 4;
  int*   idx2 = (int*)(ws + off);   off += (size_t)NQ * KNN * 4;
  float* v4   = (float*)(ws + off); off += (size_t)NQ * 4 * 4;

  float* out0 = (float*)d_out;
  float* outv = (float*)d_out + VOFF;

  k_prep<<<256, 256, 0, stream>>>(xyz1, xyz2, pts1, pts2, w_xyz, w_pts,
                                  f1b, f2b, n1, n2a, p1t, p2t, x1t, x2t);
  k_knn3<<<dim3(32, NSEG3), 256, 0, stream>>>(x1t, pd, pi);
  k_rigid<<<128, 256, 0, stream>>>(pd, pi, x1t, vel1, outv, v4);
  k_knnf_mfma<<<dim3(NQ / 16, 2), 256, 0, stream>>>(f1b, f2b, n1, n2a, pd);
  k_mergepk<0><<<128, 256, 0, stream>>>(pd, kidx);
  k_mlp_mfma<<<NQ / PPB, 512, 0, stream>>>(p1t, p2t, x1t, x2t, kidx,
                                           mlp_w1, mlp_b1, mlp_w2, mlp_b2,
                                           wn1_w1, wn1_b1, wn1_w2, wn1_b2,
                                           wn1_w3, wn1_b3, ptp);
  k_knnv<<<dim3(32, 32), 256, 0, stream>>>(v4, pd);
  k_mergepk<1><<<128, 256, 0, stream>>>(pd, idx2);
  k_final<<<NQ, 256, 0, stream>>>(x1t, idx2, ptp,
                                  wn2_w1, wn2_b1, wn2_w2, wn2_b2, wn2_w3, wn2_b3, out0);
}